// Round 1
// baseline (138.689 us; speedup 1.0000x reference)
//
#include <hip/hip_runtime.h>
#include <hip/hip_bf16.h>

// TripletBatchHardLoss: N=8192, D=256, fp32 embeddings (L2-normalized), int32 labels.
// Normalized -> pdist monotone DECREASING in dot:
//   hard_negative = max dot over negs, hard_positive = min dot over poss (diag dot~1 safe).
// R16 = LDS-FREE K-LOOP: R15's profile (MfmaUtil 14%, VALUBusy 29%, HBM 6%, occ ~25%,
// all pipes <30%) is latency-bound on the 2-barrier x 8-kt lockstep + global->LDS DMA
// round trip, not on any pipe. For mfma_16x16x32_bf16, lane l needs 16 contiguous
// aligned bytes of a row: frags load DIRECTLY global->VGPR (dwordx4 per frag), so the
// K-loop has NO LDS, NO barriers, NO DMA -- waves fully independent, register
// double-buffer gives 1-body prefetch slack, compiler inserts fine-grained vmcnt.
// Loop-invariant per-lane frag pointers (kt folds into the 13-bit imm offset: kt*64B).
// Epilogue (verified m89 C/D layout, DPP/shfl reductions, LDS combine, 8 atomic
// wave-instrs) kept identical from R15; combine scratch is its own 4 KB __shared__.
// VGPR: acc 64 (AGPR) + 64 frag + 16 ptr + misc ~ 164 unified -> fits (256,3), no spill.
// No __threadfence in wide kernels (R11: per-block fence = per-XCD L2 writeback, +130 us).

#define NS 8192
#define DD 256
#define EPS_PD 1e-12f
#define BIGF 1e30f

typedef unsigned short u16;
typedef unsigned int u32;
typedef short short8 __attribute__((ext_vector_type(8)));
typedef float f32x4 __attribute__((ext_vector_type(4)));

// order-preserving float <-> uint key (unsigned compare == float compare)
__device__ __forceinline__ u32 fkey(float f) {
    u32 b = __float_as_uint(f);
    return (b & 0x80000000u) ? ~b : (b | 0x80000000u);
}
__device__ __forceinline__ float unkey(u32 k) {
    u32 b = (k & 0x80000000u) ? (k ^ 0x80000000u) : ~k;
    return __uint_as_float(b);
}

__device__ __forceinline__ u16 f2bf_rne(float f) {
    u32 b = __float_as_uint(f);
    b += 0x7FFFu + ((b >> 16) & 1u);
    return (u16)(b >> 16);
}

// DPP lane-move within 16-lane rows (reduction groups are exactly DPP rows)
template <int CTRL>
__device__ __forceinline__ float dpp_mov(float x) {
    return __int_as_float(
        __builtin_amdgcn_update_dpp(0, __float_as_int(x), CTRL, 0xF, 0xF, true));
}

// ---------------- kernel 1: fp32 -> bf16, row sum-of-squares, init keys ----------------
__global__ __launch_bounds__(256) void prep_kernel(
    const float* __restrict__ e, u16* __restrict__ ebf, float* __restrict__ sq,
    u32* __restrict__ mxk, u32* __restrict__ mnk, float* __restrict__ out) {
    const int tid = blockIdx.x * 256 + threadIdx.x;   // 2048 blocks
    const int row = tid >> 6, t = tid & 63;           // one wave per row
    float4 v = ((const float4*)(e + (size_t)row * DD))[t];
    ushort4 u;
    u.x = f2bf_rne(v.x); u.y = f2bf_rne(v.y); u.z = f2bf_rne(v.z); u.w = f2bf_rne(v.w);
    ((ushort4*)(ebf + (size_t)row * DD))[t] = u;
    float s = v.x * v.x + v.y * v.y + v.z * v.z + v.w * v.w;
    for (int o = 32; o; o >>= 1) s += __shfl_down(s, o);
    if (t == 0) {
        sq[row] = s;
        mxk[row] = 0u;            // sentinel for unsigned max
        mnk[row] = 0xFFFFFFFFu;   // sentinel for unsigned min
        if (row == 0) out[0] = 0.0f;
    }
}

// ---------------- kernel 2: LDS-free triangular dot-GEMM + two-sided masked reduction ----
__global__ __launch_bounds__(256, 3) void tile_kernel(
    const u16* __restrict__ ebf, const int* __restrict__ labels,
    u32* __restrict__ mxk, u32* __restrict__ mnk) {
    __shared__ float red[1024];   // 4 KB epilogue combine scratch

    // decode linear triangle index -> (i <= j)
    const int t = blockIdx.x;
    int j = (int)((sqrtf(8.0f * (float)t + 1.0f) - 1.0f) * 0.5f);
    while ((j + 1) * (j + 2) / 2 <= t) ++j;
    while (j * (j + 1) / 2 > t) --j;
    const int i = t - j * (j + 1) / 2;
    const int bi = i * 128, bj = j * 128;

    const int tid = threadIdx.x;
    const int lane = tid & 63, wid = tid >> 6;
    const int wm = wid >> 1, wn = wid & 1;
    const int l15 = lane & 15, q = lane >> 4;

    // loop-invariant per-lane frag pointers; 16-B granules, 32 per row (512 B).
    // frag (mi, kt): lane l reads row (bi|bj + w*64 + mi*16 + l15), bytes q*16 + kt*64
    //  -> exactly the 8 bf16 k-elems lane l feeds to mfma_16x16x32 (q*8 within kt-tile).
    const short8* EB = (const short8*)ebf;
    const short8* pa[4];
    const short8* pb[4];
#pragma unroll
    for (int mi = 0; mi < 4; ++mi) {
        pa[mi] = EB + (size_t)(bi + wm * 64 + mi * 16 + l15) * 32 + q;
        pb[mi] = EB + (size_t)(bj + wn * 64 + mi * 16 + l15) * 32 + q;
    }

    // register double-buffer: prologue fills buf0, body kt prefetches kt+1 into the
    // other buffer before issuing kt's MFMAs (1-body slack; 3 indep waves/SIMD hide rest)
    short8 a0[4], b0[4], a1[4], b1[4];
#pragma unroll
    for (int mi = 0; mi < 4; ++mi) { a0[mi] = pa[mi][0]; b0[mi] = pb[mi][0]; }

    f32x4 acc[4][4] = {};
#pragma unroll
    for (int kt = 0; kt < 8; ++kt) {
        // static after full unroll (rule #20: no runtime-indexed reg arrays)
        short8* cura = (kt & 1) ? a1 : a0;
        short8* curb = (kt & 1) ? b1 : b0;
        short8* nxta = (kt & 1) ? a0 : a1;
        short8* nxtb = (kt & 1) ? b0 : b1;
        if (kt < 7) {
#pragma unroll
            for (int mi = 0; mi < 4; ++mi) {
                nxta[mi] = pa[mi][(kt + 1) * 4];   // imm offset kt*64 B, no addr VALU
                nxtb[mi] = pb[mi][(kt + 1) * 4];
            }
        }
#pragma unroll
        for (int mi = 0; mi < 4; ++mi)
#pragma unroll
            for (int ni = 0; ni < 4; ++ni)
                acc[mi][ni] = __builtin_amdgcn_mfma_f32_16x16x32_bf16(
                    cura[mi], curb[ni], acc[mi][ni], 0, 0, 0);
    }

    // ---- epilogue: C/D layout col = lane&15, row = q*4 + reg (m89-verified) ----
    int li[4][4];
#pragma unroll
    for (int mi = 0; mi < 4; ++mi) {
        const int4 v = *(const int4*)(labels + bi + wm * 64 + mi * 16 + q * 4);
        li[mi][0] = v.x; li[mi][1] = v.y; li[mi][2] = v.z; li[mi][3] = v.w;
    }
    int lj[4];
#pragma unroll
    for (int ni = 0; ni < 4; ++ni) lj[ni] = labels[bj + wn * 64 + ni * 16 + l15];

    float mxn[4][4], mnp[4][4];                        // row-side per (mi, r)
    float mxc[4] = {-BIGF, -BIGF, -BIGF, -BIGF};       // col-side per ni
    float mnc[4] = {BIGF, BIGF, BIGF, BIGF};
#pragma unroll
    for (int mi = 0; mi < 4; ++mi)
#pragma unroll
        for (int r2 = 0; r2 < 4; ++r2) { mxn[mi][r2] = -BIGF; mnp[mi][r2] = BIGF; }

#pragma unroll
    for (int mi = 0; mi < 4; ++mi)
#pragma unroll
        for (int ni = 0; ni < 4; ++ni) {
            const int l = lj[ni];
#pragma unroll
            for (int r2 = 0; r2 < 4; ++r2) {
                const float d = acc[mi][ni][r2];
                const bool same = (li[mi][r2] == l);
                const float sneg = same ? -BIGF : d;
                const float spos = same ? d : BIGF;
                mxn[mi][r2] = fmaxf(mxn[mi][r2], sneg);
                mnp[mi][r2] = fminf(mnp[mi][r2], spos);
                mxc[ni] = fmaxf(mxc[ni], sneg);
                mnc[ni] = fminf(mnc[ni], spos);
            }
        }

    // col-side: reduce over q (lanes l15, +16, +32, +48) via shfl_xor 16/32
#pragma unroll
    for (int ni = 0; ni < 4; ++ni) {
        mxc[ni] = fmaxf(mxc[ni], __shfl_xor(mxc[ni], 16));
        mnc[ni] = fminf(mnc[ni], __shfl_xor(mnc[ni], 16));
        mxc[ni] = fmaxf(mxc[ni], __shfl_xor(mxc[ni], 32));
        mnc[ni] = fminf(mnc[ni], __shfl_xor(mnc[ni], 32));
    }
    // row-side: 16-lane DPP reduction (xor1, xor2, ror4, ror8)
#pragma unroll
    for (int mi = 0; mi < 4; ++mi)
#pragma unroll
        for (int r2 = 0; r2 < 4; ++r2) {
            float x = mxn[mi][r2], n = mnp[mi][r2];
            x = fmaxf(x, dpp_mov<0xB1>(x));  n = fminf(n, dpp_mov<0xB1>(n));
            x = fmaxf(x, dpp_mov<0x4E>(x));  n = fminf(n, dpp_mov<0x4E>(n));
            x = fmaxf(x, dpp_mov<0x124>(x)); n = fminf(n, dpp_mov<0x124>(n));
            x = fmaxf(x, dpp_mov<0x128>(x)); n = fminf(n, dpp_mov<0x128>(n));
            mxn[mi][r2] = x; mnp[mi][r2] = n;
        }

    // ---- block-level LDS combine -> 8 atomic wave-instrs total ----
    // Layout (floats): [0..255] rowmax[row][wn], [256..511] rowmin,
    // [512..767] colmax[col][wm], [768..1023] colmin.
    if (l15 == 0) {
#pragma unroll
        for (int mi = 0; mi < 4; ++mi)
#pragma unroll
            for (int r2 = 0; r2 < 4; ++r2) {
                const int rl = wm * 64 + mi * 16 + q * 4 + r2;
                red[rl * 2 + wn] = mxn[mi][r2];
                red[256 + rl * 2 + wn] = mnp[mi][r2];
            }
    }
    if (q == 0) {
#pragma unroll
        for (int ni = 0; ni < 4; ++ni) {
            const int cl = wn * 64 + ni * 16 + l15;
            red[512 + cl * 2 + wm] = mxc[ni];
            red[768 + cl * 2 + wm] = mnc[ni];
        }
    }
    __syncthreads();
    if (tid < 128) {
        const float mx = fmaxf(red[tid * 2], red[tid * 2 + 1]);
        const float mn = fminf(red[256 + tid * 2], red[256 + tid * 2 + 1]);
        atomicMax(&mxk[bi + tid], fkey(mx));
        atomicMin(&mnk[bi + tid], fkey(mn));
    } else {
        const int c = tid - 128;
        const float mx = fmaxf(red[512 + c * 2], red[512 + c * 2 + 1]);
        const float mn = fminf(red[768 + c * 2], red[768 + c * 2 + 1]);
        atomicMax(&mxk[bj + c], fkey(mx));
        atomicMin(&mnk[bj + c], fkey(mn));
    }
}

// ---------------- kernel 3: per-row loss + mean ----------------
__global__ __launch_bounds__(256) void finalize_kernel(
    const u32* __restrict__ mxk, const u32* __restrict__ mnk,
    const float* __restrict__ sq, float* __restrict__ out) {
    const int i = blockIdx.x * 256 + threadIdx.x;
    const float s = sq[i] + 1.0f;   // sq_i + sq_j, sq_j = 1 +- 1e-7
    const float hn = sqrtf(fmaxf(fmaf(-2.0f, unkey(mxk[i]), s), EPS_PD));
    const float hp = sqrtf(fmaxf(fmaf(-2.0f, unkey(mnk[i]), s), EPS_PD));
    float loss = fmaxf(hp - hn + 1.0f, 0.0f);
    for (int o = 32; o; o >>= 1) loss += __shfl_down(loss, o);
    __shared__ float wsum[4];
    const int lane = threadIdx.x & 63, w = threadIdx.x >> 6;
    if (lane == 0) wsum[w] = loss;
    __syncthreads();
    if (threadIdx.x == 0)
        atomicAdd(out, (wsum[0] + wsum[1] + wsum[2] + wsum[3]) * (1.0f / NS));
}

extern "C" void kernel_launch(void* const* d_in, const int* in_sizes, int n_in,
                              void* d_out, int out_size, void* d_ws, size_t ws_size,
                              hipStream_t stream) {
    const int* labels = (const int*)d_in[0];
    const float* emb = (const float*)d_in[1];
    float* out = (float*)d_out;

    char* ws = (char*)d_ws;
    u16* ebf = (u16*)ws;                                     // 4 MB
    float* sq = (float*)(ws + (size_t)NS * DD * 2);          // 32 KB
    u32* mxk = (u32*)(ws + (size_t)NS * DD * 2 + NS * 4);
    u32* mnk = mxk + NS;

    prep_kernel<<<NS * DD / 4 / 256, 256, 0, stream>>>(emb, ebf, sq, mxk, mnk, out);
    tile_kernel<<<2080, 256, 0, stream>>>(ebf, labels, mxk, mnk);
    finalize_kernel<<<NS / 256, 256, 0, stream>>>(mxk, mnk, sq, out);
}

// Round 2
// 102.271 us; speedup vs baseline: 1.3561x; 1.3561x over previous
//
#include <hip/hip_runtime.h>
#include <hip/hip_bf16.h>

// TripletBatchHardLoss: N=8192, D=256, fp32 embeddings (L2-normalized), int32 labels.
// Normalized -> pdist monotone DECREASING in dot:
//   hard_negative = max dot over negs, hard_positive = min dot over poss (diag dot~1 safe).
// R17 = R15's verified dbuf/counted-vmcnt sync structure SCALED to 128x256 tiles, 4 waves:
//   - R16 post-mortem: LDS-free global->VGPR frags regressed 44.9->78.4 us (MfmaUtil 8%,
//     all pipes idle) -- 16-line-per-lane loads with 1-body slack expose full L2 latency.
//     Staging via global_load_lds was never the problem; barrier density was.
//   - Each wave owns 128 rows x 64 cols (acc[8][4]): 32 MFMA per barrier-pair (2x R15),
//     body issue time now ~covers DMA latency inside the 1-body prefetch slack.
//   - 1056 tiles (64x32 rect grid clipped to triangle, I <= 2J+1) vs 2080: half the
//     per-block decode/prologue/epilogue instances, same 34.6M output elements.
//   - 54 KB LDS, launch_bounds(256,2) -> 2 INDEPENDENT blocks/CU: co-resident blocks are
//     desynced, one block's vmcnt/barrier stall is filled by the other's MFMAs (m114).
// Coverage: pair (r<c) lives in tile (I=r>>7, J=c>>8), included since I<=2J+1; row-side
// updates row r, col-side updates col c. Sub-diagonal duplicates are idempotent max/min.
// VGPR discipline: acc 128 (AGPR) + ~100 arch under the (256,2)=256 unified cap.
// No __threadfence in wide kernels (R11: per-block fence = per-XCD L2 writeback, +130 us).

#define NS 8192
#define DD 256
#define NT 1056
#define EPS_PD 1e-12f
#define BIGF 1e30f

typedef unsigned short u16;
typedef unsigned int u32;
typedef short short8 __attribute__((ext_vector_type(8)));
typedef float f32x4 __attribute__((ext_vector_type(4)));

typedef const __attribute__((address_space(1))) u32 glb_u32;
typedef __attribute__((address_space(3))) u32 lds_u32;

__device__ __forceinline__ void async16(const void* g, void* l) {
    __builtin_amdgcn_global_load_lds((glb_u32*)g, (lds_u32*)l, 16, 0, 0);
}

// order-preserving float <-> uint key (unsigned compare == float compare)
__device__ __forceinline__ u32 fkey(float f) {
    u32 b = __float_as_uint(f);
    return (b & 0x80000000u) ? ~b : (b | 0x80000000u);
}
__device__ __forceinline__ float unkey(u32 k) {
    u32 b = (k & 0x80000000u) ? (k ^ 0x80000000u) : ~k;
    return __uint_as_float(b);
}

__device__ __forceinline__ u16 f2bf_rne(float f) {
    u32 b = __float_as_uint(f);
    b += 0x7FFFu + ((b >> 16) & 1u);
    return (u16)(b >> 16);
}

// DPP lane-move within 16-lane rows (reduction groups are exactly DPP rows)
template <int CTRL>
__device__ __forceinline__ float dpp_mov(float x) {
    return __int_as_float(
        __builtin_amdgcn_update_dpp(0, __float_as_int(x), CTRL, 0xF, 0xF, true));
}

// ---------------- kernel 1: fp32 -> bf16, row sum-of-squares, init keys ----------------
__global__ __launch_bounds__(256) void prep_kernel(
    const float* __restrict__ e, u16* __restrict__ ebf, float* __restrict__ sq,
    u32* __restrict__ mxk, u32* __restrict__ mnk, float* __restrict__ out) {
    const int tid = blockIdx.x * 256 + threadIdx.x;   // 2048 blocks
    const int row = tid >> 6, t = tid & 63;           // one wave per row
    float4 v = ((const float4*)(e + (size_t)row * DD))[t];
    ushort4 u;
    u.x = f2bf_rne(v.x); u.y = f2bf_rne(v.y); u.z = f2bf_rne(v.z); u.w = f2bf_rne(v.w);
    ((ushort4*)(ebf + (size_t)row * DD))[t] = u;
    float s = v.x * v.x + v.y * v.y + v.z * v.z + v.w * v.w;
    for (int o = 32; o; o >>= 1) s += __shfl_down(s, o);
    if (t == 0) {
        sq[row] = s;
        mxk[row] = 0u;            // sentinel for unsigned max
        mnk[row] = 0xFFFFFFFFu;   // sentinel for unsigned min
        if (row == 0) out[0] = 0.0f;
    }
}

// ---------------- kernel 2: dbuf 128x256 dot-GEMM + two-sided masked reduction ----------
__global__ __launch_bounds__(256, 2) void tile_kernel(
    const u16* __restrict__ ebf, const int* __restrict__ labels,
    u32* __restrict__ mxk, u32* __restrict__ mnk) {
    // A: 128x32 (512 slots), B: 256x32 (1024 slots); 16B chunk (row,c) at
    // slot row*4 + (c ^ ((row>>2)&3))  -> 2-way bank alias on ds_read_b128 (free, m136)
    __shared__ __attribute__((aligned(16))) u16 lds_a[2][4096];   // 2 x 8 KB
    __shared__ __attribute__((aligned(16))) u16 lds_b[2][8192];   // 2 x 16 KB
    __shared__ float red[1536];                                    // 6 KB combine scratch

    // decode linear clipped-grid index -> (I, J), cum(J) = J*(J+1), I in [0, 2J+2)
    const int t = blockIdx.x;
    int j = (int)((sqrtf(4.0f * (float)t + 1.0f) - 1.0f) * 0.5f);
    while ((j + 1) * (j + 2) <= t) ++j;
    while (j * (j + 1) > t) --j;
    const int i = t - j * (j + 1);
    const int bi = i * 128, bj = j * 256;

    const int tid = threadIdx.x;
    const int lane = tid & 63, wid = tid >> 6;        // 4 waves
    const int l15 = lane & 15, q = lane >> 4;

    // staging: wave wid owns A slots [wid*128, +128) (2 DMAs) and B slots [wid*256, +256)
    // (4 DMAs); per-lane global source is swizzle-permuted within each 64B row-chunk.
    const u16* gA[2];
#pragma unroll
    for (int p = 0; p < 2; ++p) {
        const int s = wid * 128 + p * 64 + lane;
        const int r = s >> 2, c = (s & 3) ^ ((r >> 2) & 3);
        gA[p] = ebf + (size_t)(bi + r) * DD + c * 8;
    }
    const u16* gB[4];
#pragma unroll
    for (int p = 0; p < 4; ++p) {
        const int s = wid * 256 + p * 64 + lane;
        const int r = s >> 2, c = (s & 3) ^ ((r >> 2) & 3);
        gB[p] = ebf + (size_t)(bj + r) * DD + c * 8;
    }

    // frag-read offsets (u16 elems): row = base + l15, chunk q -> slot row*4 + (q^((row>>2)&3))
    const int swz = (q ^ (l15 >> 2)) * 8;
    const int offa = l15 * 32 + swz;                  // + mi*512, rows mi*16 + l15
    const int offb = (wid * 64 + l15) * 32 + swz;     // + ni*512, cols wid*64 + ni*16 + l15

    // 6 DMAs per wave per K-step; LDS dests are wave-uniform bases (HW adds lane*16B)
#define ISSUE_TILE(buf, ko)                                              \
    do {                                                                 \
        async16(gA[0] + (ko), &lds_a[buf][(wid * 128) * 8]);             \
        async16(gA[1] + (ko), &lds_a[buf][(wid * 128 + 64) * 8]);        \
        async16(gB[0] + (ko), &lds_b[buf][(wid * 256) * 8]);             \
        async16(gB[1] + (ko), &lds_b[buf][(wid * 256 + 64) * 8]);        \
        async16(gB[2] + (ko), &lds_b[buf][(wid * 256 + 128) * 8]);       \
        async16(gB[3] + (ko), &lds_b[buf][(wid * 256 + 192) * 8]);       \
    } while (0)

    // prologue: DMA K-step 0 into buffer 0
    ISSUE_TILE(0, 0);

    f32x4 acc[8][4] = {};
#pragma unroll
    for (int kt = 0; kt < 8; ++kt) {
        const int cur = kt & 1, nxt = cur ^ 1;
        if (kt < 7) {   // prefetch step kt+1 (issued BEFORE the wait), then drain kt's 6
            ISSUE_TILE(nxt, (kt + 1) * 32);
            asm volatile("s_waitcnt vmcnt(6)\n\ts_barrier" ::: "memory");
        } else {
            asm volatile("s_waitcnt vmcnt(0)\n\ts_barrier" ::: "memory");
        }
        short8 af[8], bfr[4];
#pragma unroll
        for (int mi = 0; mi < 8; ++mi)
            af[mi] = *(const short8*)(&lds_a[cur][offa + mi * 512]);
#pragma unroll
        for (int ni = 0; ni < 4; ++ni)
            bfr[ni] = *(const short8*)(&lds_b[cur][offb + ni * 512]);
#pragma unroll
        for (int mi = 0; mi < 8; ++mi)
#pragma unroll
            for (int ni = 0; ni < 4; ++ni)
                acc[mi][ni] = __builtin_amdgcn_mfma_f32_16x16x32_bf16(
                    af[mi], bfr[ni], acc[mi][ni], 0, 0, 0);
        if (kt < 7) {
            // WAR guard: all waves done reading buf[cur] before body kt+1's DMA clobbers it
            asm volatile("s_waitcnt lgkmcnt(0)\n\ts_barrier" ::: "memory");
        }
    }

    // ---- epilogue: C/D layout col = lane&15, row = q*4 + reg (m89-verified) ----
    int lj[4];
#pragma unroll
    for (int ni = 0; ni < 4; ++ni) lj[ni] = labels[bj + wid * 64 + ni * 16 + l15];

    float mxn[8][4], mnp[8][4];                        // row-side per (mi, r)
    float mxc[4] = {-BIGF, -BIGF, -BIGF, -BIGF};       // col-side per ni
    float mnc[4] = {BIGF, BIGF, BIGF, BIGF};
#pragma unroll
    for (int mi = 0; mi < 8; ++mi)
#pragma unroll
        for (int r2 = 0; r2 < 4; ++r2) { mxn[mi][r2] = -BIGF; mnp[mi][r2] = BIGF; }

#pragma unroll
    for (int mi = 0; mi < 8; ++mi) {
        const int4 v = *(const int4*)(labels + bi + mi * 16 + q * 4);
        const int li0 = v.x, li1 = v.y, li2 = v.z, li3 = v.w;
#pragma unroll
        for (int ni = 0; ni < 4; ++ni) {
            const int l = lj[ni];
#pragma unroll
            for (int r2 = 0; r2 < 4; ++r2) {
                const int lr = (r2 == 0) ? li0 : (r2 == 1) ? li1 : (r2 == 2) ? li2 : li3;
                const float d = acc[mi][ni][r2];
                const bool same = (lr == l);
                const float sneg = same ? -BIGF : d;
                const float spos = same ? d : BIGF;
                mxn[mi][r2] = fmaxf(mxn[mi][r2], sneg);
                mnp[mi][r2] = fminf(mnp[mi][r2], spos);
                mxc[ni] = fmaxf(mxc[ni], sneg);
                mnc[ni] = fminf(mnc[ni], spos);
            }
        }
    }

    // col-side: reduce over q (lanes l15, +16, +32, +48) via shfl_xor 16/32
#pragma unroll
    for (int ni = 0; ni < 4; ++ni) {
        mxc[ni] = fmaxf(mxc[ni], __shfl_xor(mxc[ni], 16));
        mnc[ni] = fminf(mnc[ni], __shfl_xor(mnc[ni], 16));
        mxc[ni] = fmaxf(mxc[ni], __shfl_xor(mxc[ni], 32));
        mnc[ni] = fminf(mnc[ni], __shfl_xor(mnc[ni], 32));
    }
    // row-side: 16-lane DPP reduction (xor1, xor2, ror4, ror8)
#pragma unroll
    for (int mi = 0; mi < 8; ++mi)
#pragma unroll
        for (int r2 = 0; r2 < 4; ++r2) {
            float x = mxn[mi][r2], n = mnp[mi][r2];
            x = fmaxf(x, dpp_mov<0xB1>(x));  n = fminf(n, dpp_mov<0xB1>(n));
            x = fmaxf(x, dpp_mov<0x4E>(x));  n = fminf(n, dpp_mov<0x4E>(n));
            x = fmaxf(x, dpp_mov<0x124>(x)); n = fminf(n, dpp_mov<0x124>(n));
            x = fmaxf(x, dpp_mov<0x128>(x)); n = fminf(n, dpp_mov<0x128>(n));
            mxn[mi][r2] = x; mnp[mi][r2] = n;
        }

    // ---- block-level LDS combine -> 12 atomic wave-instrs total ----
    // Layout (floats): [0..511] rowmax[row][wid], [512..1023] rowmin,
    // [1024..1279] colmax[col], [1280..1535] colmin (cols owned by one wave each).
    if (l15 == 0) {
#pragma unroll
        for (int mi = 0; mi < 8; ++mi)
#pragma unroll
            for (int r2 = 0; r2 < 4; ++r2) {
                const int rl = mi * 16 + q * 4 + r2;
                red[rl * 4 + wid] = mxn[mi][r2];
                red[512 + rl * 4 + wid] = mnp[mi][r2];
            }
    }
    if (q == 0) {
#pragma unroll
        for (int ni = 0; ni < 4; ++ni) {
            const int cl = wid * 64 + ni * 16 + l15;
            red[1024 + cl] = mxc[ni];
            red[1280 + cl] = mnc[ni];
        }
    }
    __syncthreads();
    if (tid < 128) {
        const float4 a = *(const float4*)&red[tid * 4];
        const float4 b = *(const float4*)&red[512 + tid * 4];
        const float mx = fmaxf(fmaxf(a.x, a.y), fmaxf(a.z, a.w));
        const float mn = fminf(fminf(b.x, b.y), fminf(b.z, b.w));
        atomicMax(&mxk[bi + tid], fkey(mx));
        atomicMin(&mnk[bi + tid], fkey(mn));
    } else {
        const int c = tid - 128;   // handles cols c and c+128
        atomicMax(&mxk[bj + c], fkey(red[1024 + c]));
        atomicMin(&mnk[bj + c], fkey(red[1280 + c]));
        atomicMax(&mxk[bj + 128 + c], fkey(red[1152 + c]));
        atomicMin(&mnk[bj + 128 + c], fkey(red[1408 + c]));
    }
}

// ---------------- kernel 3: per-row loss + mean ----------------
__global__ __launch_bounds__(256) void finalize_kernel(
    const u32* __restrict__ mxk, const u32* __restrict__ mnk,
    const float* __restrict__ sq, float* __restrict__ out) {
    const int i = blockIdx.x * 256 + threadIdx.x;
    const float s = sq[i] + 1.0f;   // sq_i + sq_j, sq_j = 1 +- 1e-7
    const float hn = sqrtf(fmaxf(fmaf(-2.0f, unkey(mxk[i]), s), EPS_PD));
    const float hp = sqrtf(fmaxf(fmaf(-2.0f, unkey(mnk[i]), s), EPS_PD));
    float loss = fmaxf(hp - hn + 1.0f, 0.0f);
    for (int o = 32; o; o >>= 1) loss += __shfl_down(loss, o);
    __shared__ float wsum[4];
    const int lane = threadIdx.x & 63, w = threadIdx.x >> 6;
    if (lane == 0) wsum[w] = loss;
    __syncthreads();
    if (threadIdx.x == 0)
        atomicAdd(out, (wsum[0] + wsum[1] + wsum[2] + wsum[3]) * (1.0f / NS));
}

extern "C" void kernel_launch(void* const* d_in, const int* in_sizes, int n_in,
                              void* d_out, int out_size, void* d_ws, size_t ws_size,
                              hipStream_t stream) {
    const int* labels = (const int*)d_in[0];
    const float* emb = (const float*)d_in[1];
    float* out = (float*)d_out;

    char* ws = (char*)d_ws;
    u16* ebf = (u16*)ws;                                     // 4 MB
    float* sq = (float*)(ws + (size_t)NS * DD * 2);          // 32 KB
    u32* mxk = (u32*)(ws + (size_t)NS * DD * 2 + NS * 4);
    u32* mnk = mxk + NS;

    prep_kernel<<<NS * DD / 4 / 256, 256, 0, stream>>>(emb, ebf, sq, mxk, mnk, out);
    tile_kernel<<<NT, 256, 0, stream>>>(ebf, labels, mxk, mnk);
    finalize_kernel<<<NS / 256, 256, 0, stream>>>(mxk, mnk, sq, out);
}

// Round 3
// 99.038 us; speedup vs baseline: 1.4004x; 1.0326x over previous
//
#include <hip/hip_runtime.h>
#include <hip/hip_bf16.h>

// TripletBatchHardLoss: N=8192, D=256, fp32 embeddings (L2-normalized), int32 labels.
// Normalized -> pdist monotone DECREASING in dot:
//   hard_negative = max dot over negs, hard_positive = min dot over poss (diag dot~1 safe).
// R18 = R15's exact 128x128 shape (2080 tri blocks, 4 waves, 3 blocks/CU, 12 waves/CU)
// with the sync structure rebuilt as a 3-BUFFER ROTATION, ONE barrier per K-step:
//   - R16/R17 post-mortem: perf tracks independent co-resident waves (R15 12 waves/CU =
//     44.9us; R17 8-wave-capacity but ~5 effective = 56.6us; R16 no-LDS = 78us). Keep
//     R15 occupancy, cut the per-kt sync cost instead.
//   - Old: [issue kt+1; vmcnt(4); barrier; reads; MFMA; lgkmcnt(0); barrier] x8 -- the
//     trailing full-LDS-drain barrier serialized every step.
//   - New: [vmcnt(4); barrier; issue kt+2 -> buf (kt+2)%3; reads buf kt%3; MFMA] x8.
//     WAR safe: buf (kt+2)%3 == buf (kt-1)%3, whose reads retired before each wave's
//     kt-1 MFMAs, which precede barrier kt (collective) -- so post-barrier DMA cannot
//     clobber in-flight reads. Per-wave vmcnt: drain own kt-batch BEFORE barrier,
//     read after -> cross-wave LDS visibility holds.
//   - Prefetch slack doubles to 2 bodies (~500+cyc, covers L2 latency); steady-state
//     wait stays counted at vmcnt(4); no lgkm full-drain anywhere (compiler emits
//     fine-grained lgkmcnt for ds_read->MFMA).
//   - LDS 3x16KB = 48KB, scratch reuses buf0's A region (body-7 reads live in buf1
//     only; epilogue begins after barrier 7). 48KB x 3 = 144KB fits 160KB/CU.
// VGPR discipline: (256,3) = 72V + 64A, no spills (R15-verified).
// No __threadfence in wide kernels (R11: per-block fence = per-XCD L2 writeback, +130 us).

#define NS 8192
#define DD 256
#define EPS_PD 1e-12f
#define BIGF 1e30f

typedef unsigned short u16;
typedef unsigned int u32;
typedef short short8 __attribute__((ext_vector_type(8)));
typedef float f32x4 __attribute__((ext_vector_type(4)));

typedef const __attribute__((address_space(1))) u32 glb_u32;
typedef __attribute__((address_space(3))) u32 lds_u32;

__device__ __forceinline__ void async16(const void* g, void* l) {
    __builtin_amdgcn_global_load_lds((glb_u32*)g, (lds_u32*)l, 16, 0, 0);
}

// order-preserving float <-> uint key (unsigned compare == float compare)
__device__ __forceinline__ u32 fkey(float f) {
    u32 b = __float_as_uint(f);
    return (b & 0x80000000u) ? ~b : (b | 0x80000000u);
}
__device__ __forceinline__ float unkey(u32 k) {
    u32 b = (k & 0x80000000u) ? (k ^ 0x80000000u) : ~k;
    return __uint_as_float(b);
}

__device__ __forceinline__ u16 f2bf_rne(float f) {
    u32 b = __float_as_uint(f);
    b += 0x7FFFu + ((b >> 16) & 1u);
    return (u16)(b >> 16);
}

// DPP lane-move within 16-lane rows (reduction groups are exactly DPP rows)
template <int CTRL>
__device__ __forceinline__ float dpp_mov(float x) {
    return __int_as_float(
        __builtin_amdgcn_update_dpp(0, __float_as_int(x), CTRL, 0xF, 0xF, true));
}

// ---------------- kernel 1: fp32 -> bf16, row sum-of-squares, init keys ----------------
__global__ __launch_bounds__(256) void prep_kernel(
    const float* __restrict__ e, u16* __restrict__ ebf, float* __restrict__ sq,
    u32* __restrict__ mxk, u32* __restrict__ mnk, float* __restrict__ out) {
    const int tid = blockIdx.x * 256 + threadIdx.x;   // 2048 blocks
    const int row = tid >> 6, t = tid & 63;           // one wave per row
    float4 v = ((const float4*)(e + (size_t)row * DD))[t];
    ushort4 u;
    u.x = f2bf_rne(v.x); u.y = f2bf_rne(v.y); u.z = f2bf_rne(v.z); u.w = f2bf_rne(v.w);
    ((ushort4*)(ebf + (size_t)row * DD))[t] = u;
    float s = v.x * v.x + v.y * v.y + v.z * v.z + v.w * v.w;
    for (int o = 32; o; o >>= 1) s += __shfl_down(s, o);
    if (t == 0) {
        sq[row] = s;
        mxk[row] = 0u;            // sentinel for unsigned max
        mnk[row] = 0xFFFFFFFFu;   // sentinel for unsigned min
        if (row == 0) out[0] = 0.0f;
    }
}

// ---------------- kernel 2: 3-buf triangular dot-GEMM + two-sided masked reduction -------
__global__ __launch_bounds__(256, 3) void tile_kernel(
    const u16* __restrict__ ebf, const int* __restrict__ labels,
    u32* __restrict__ mxk, u32* __restrict__ mnk) {
    // 3 x (128x32) tiles each; 16B chunk (row,c) at slot row*4 + (c^((row>>2)&3))
    __shared__ __attribute__((aligned(16))) u16 lds_a[3][128 * 32];   // 3 x 8 KB
    __shared__ __attribute__((aligned(16))) u16 lds_b[3][128 * 32];   // 3 x 8 KB

    // decode linear triangle index -> (i <= j)
    const int t = blockIdx.x;
    int j = (int)((sqrtf(8.0f * (float)t + 1.0f) - 1.0f) * 0.5f);
    while ((j + 1) * (j + 2) / 2 <= t) ++j;
    while (j * (j + 1) / 2 > t) --j;
    const int i = t - j * (j + 1) / 2;
    const int bi = i * 128, bj = j * 128;

    const int tid = threadIdx.x;
    const int lane = tid & 63, wid = tid >> 6;
    const int wm = wid >> 1, wn = wid & 1;
    const int l15 = lane & 15, q = lane >> 4;

    // staging: wave wid owns slots [wid*128, wid*128+128) of each 512-slot tile
    const int s0 = wid * 128 + lane, s1 = s0 + 64;
    const int r0 = s0 >> 2, c0 = (s0 & 3) ^ ((r0 >> 2) & 3);
    const int r1 = s1 >> 2, c1 = (s1 & 3) ^ ((r1 >> 2) & 3);
    const u16* gA0 = ebf + (size_t)(bi + r0) * DD + c0 * 8;
    const u16* gA1 = ebf + (size_t)(bi + r1) * DD + c1 * 8;
    const u16* gB0 = ebf + (size_t)(bj + r0) * DD + c0 * 8;
    const u16* gB1 = ebf + (size_t)(bj + r1) * DD + c1 * 8;
    const int ldst0 = wid * 128 * 8, ldst1 = ldst0 + 64 * 8;

    // frag-read offsets (u16 elems): row = base+l15, chunk q -> slot row*4 + (q^((row>>2)&3))
    const int swz = (q ^ (l15 >> 2)) * 8;
    const int offa = (wm * 64 + l15) * 32 + swz;
    const int offb = (wn * 64 + l15) * 32 + swz;

#define ISSUE_TILE(buf, ko)                                   \
    do {                                                      \
        async16(gA0 + (ko), &lds_a[buf][ldst0]);              \
        async16(gA1 + (ko), &lds_a[buf][ldst1]);              \
        async16(gB0 + (ko), &lds_b[buf][ldst0]);              \
        async16(gB1 + (ko), &lds_b[buf][ldst1]);              \
    } while (0)

    // prologue: DMA K-steps 0 and 1 into buffers 0 and 1 (8 DMAs in flight per wave)
    ISSUE_TILE(0, 0);
    ISSUE_TILE(1, 32);

    f32x4 acc[4][4] = {};
#pragma unroll
    for (int kt = 0; kt < 8; ++kt) {
        const int cur = kt % 3;   // static after full unroll
        // drain own kt-batch (keep kt+1 and, soon, kt+2 in flight), then sync.
        if (kt < 7)
            asm volatile("s_waitcnt vmcnt(4)\n\ts_barrier" ::: "memory");
        else
            asm volatile("s_waitcnt vmcnt(0)\n\ts_barrier" ::: "memory");
        // post-barrier prefetch of kt+2 into buf (kt+2)%3 == (kt-1)%3: all waves'
        // kt-1 reads retired before barrier kt -> WAR-safe; 2-body latency slack.
        if (kt < 6) ISSUE_TILE((kt + 2) % 3, (kt + 2) * 32);
        short8 af[4], bfr[4];
#pragma unroll
        for (int mi = 0; mi < 4; ++mi)
            af[mi] = *(const short8*)(&lds_a[cur][offa + mi * 512]);
#pragma unroll
        for (int ni = 0; ni < 4; ++ni)
            bfr[ni] = *(const short8*)(&lds_b[cur][offb + ni * 512]);
#pragma unroll
        for (int mi = 0; mi < 4; ++mi)
#pragma unroll
            for (int ni = 0; ni < 4; ++ni)
                acc[mi][ni] = __builtin_amdgcn_mfma_f32_16x16x32_bf16(
                    af[mi], bfr[ni], acc[mi][ni], 0, 0, 0);
        // no trailing barrier, no lgkm full-drain: compiler handles ds_read->MFMA waits
    }

    // ---- epilogue: C/D layout col = lane&15, row = q*4 + reg (m89-verified) ----
    int li[4][4];
#pragma unroll
    for (int mi = 0; mi < 4; ++mi) {
        const int4 v = *(const int4*)(labels + bi + wm * 64 + mi * 16 + q * 4);
        li[mi][0] = v.x; li[mi][1] = v.y; li[mi][2] = v.z; li[mi][3] = v.w;
    }
    int lj[4];
#pragma unroll
    for (int ni = 0; ni < 4; ++ni) lj[ni] = labels[bj + wn * 64 + ni * 16 + l15];

    float mxn[4][4], mnp[4][4];                        // row-side per (mi, r)
    float mxc[4] = {-BIGF, -BIGF, -BIGF, -BIGF};       // col-side per ni
    float mnc[4] = {BIGF, BIGF, BIGF, BIGF};
#pragma unroll
    for (int mi = 0; mi < 4; ++mi)
#pragma unroll
        for (int r2 = 0; r2 < 4; ++r2) { mxn[mi][r2] = -BIGF; mnp[mi][r2] = BIGF; }

#pragma unroll
    for (int mi = 0; mi < 4; ++mi)
#pragma unroll
        for (int ni = 0; ni < 4; ++ni) {
            const int l = lj[ni];
#pragma unroll
            for (int r2 = 0; r2 < 4; ++r2) {
                const float d = acc[mi][ni][r2];
                const bool same = (li[mi][r2] == l);
                const float sneg = same ? -BIGF : d;
                const float spos = same ? d : BIGF;
                mxn[mi][r2] = fmaxf(mxn[mi][r2], sneg);
                mnp[mi][r2] = fminf(mnp[mi][r2], spos);
                mxc[ni] = fmaxf(mxc[ni], sneg);
                mnc[ni] = fminf(mnc[ni], spos);
            }
        }

    // col-side: reduce over q (lanes l15, +16, +32, +48) via shfl_xor 16/32
#pragma unroll
    for (int ni = 0; ni < 4; ++ni) {
        mxc[ni] = fmaxf(mxc[ni], __shfl_xor(mxc[ni], 16));
        mnc[ni] = fminf(mnc[ni], __shfl_xor(mnc[ni], 16));
        mxc[ni] = fmaxf(mxc[ni], __shfl_xor(mxc[ni], 32));
        mnc[ni] = fminf(mnc[ni], __shfl_xor(mnc[ni], 32));
    }
    // row-side: 16-lane DPP reduction (xor1, xor2, ror4, ror8)
#pragma unroll
    for (int mi = 0; mi < 4; ++mi)
#pragma unroll
        for (int r2 = 0; r2 < 4; ++r2) {
            float x = mxn[mi][r2], n = mnp[mi][r2];
            x = fmaxf(x, dpp_mov<0xB1>(x));  n = fminf(n, dpp_mov<0xB1>(n));
            x = fmaxf(x, dpp_mov<0x4E>(x));  n = fminf(n, dpp_mov<0x4E>(n));
            x = fmaxf(x, dpp_mov<0x124>(x)); n = fminf(n, dpp_mov<0x124>(n));
            x = fmaxf(x, dpp_mov<0x128>(x)); n = fminf(n, dpp_mov<0x128>(n));
            mxn[mi][r2] = x; mnp[mi][r2] = n;
        }

    // ---- block-level LDS combine -> 8 atomic wave-instrs total ----
    // scratch in lds_a[0] (free: body 7 reads buffer 1 only; epilogue begins after
    // barrier 7, by which every wave's buf-0 reads (body 6) have retired).
    // Layout (floats): [0..255] rowmax[row][wn], [256..511] rowmin,
    // [512..767] colmax[col][wm], [768..1023] colmin. 4 KB.
    float* red = (float*)&lds_a[0][0];
    if (l15 == 0) {
#pragma unroll
        for (int mi = 0; mi < 4; ++mi)
#pragma unroll
            for (int r2 = 0; r2 < 4; ++r2) {
                const int rl = wm * 64 + mi * 16 + q * 4 + r2;
                red[rl * 2 + wn] = mxn[mi][r2];
                red[256 + rl * 2 + wn] = mnp[mi][r2];
            }
    }
    if (q == 0) {
#pragma unroll
        for (int ni = 0; ni < 4; ++ni) {
            const int cl = wn * 64 + ni * 16 + l15;
            red[512 + cl * 2 + wm] = mxc[ni];
            red[768 + cl * 2 + wm] = mnc[ni];
        }
    }
    __syncthreads();
    if (tid < 128) {
        const float mx = fmaxf(red[tid * 2], red[tid * 2 + 1]);
        const float mn = fminf(red[256 + tid * 2], red[256 + tid * 2 + 1]);
        atomicMax(&mxk[bi + tid], fkey(mx));
        atomicMin(&mnk[bi + tid], fkey(mn));
    } else {
        const int c = tid - 128;
        const float mx = fmaxf(red[512 + c * 2], red[512 + c * 2 + 1]);
        const float mn = fminf(red[768 + c * 2], red[768 + c * 2 + 1]);
        atomicMax(&mxk[bj + c], fkey(mx));
        atomicMin(&mnk[bj + c], fkey(mn));
    }
}

// ---------------- kernel 3: per-row loss + mean ----------------
__global__ __launch_bounds__(256) void finalize_kernel(
    const u32* __restrict__ mxk, const u32* __restrict__ mnk,
    const float* __restrict__ sq, float* __restrict__ out) {
    const int i = blockIdx.x * 256 + threadIdx.x;
    const float s = sq[i] + 1.0f;   // sq_i + sq_j, sq_j = 1 +- 1e-7
    const float hn = sqrtf(fmaxf(fmaf(-2.0f, unkey(mxk[i]), s), EPS_PD));
    const float hp = sqrtf(fmaxf(fmaf(-2.0f, unkey(mnk[i]), s), EPS_PD));
    float loss = fmaxf(hp - hn + 1.0f, 0.0f);
    for (int o = 32; o; o >>= 1) loss += __shfl_down(loss, o);
    __shared__ float wsum[4];
    const int lane = threadIdx.x & 63, w = threadIdx.x >> 6;
    if (lane == 0) wsum[w] = loss;
    __syncthreads();
    if (threadIdx.x == 0)
        atomicAdd(out, (wsum[0] + wsum[1] + wsum[2] + wsum[3]) * (1.0f / NS));
}

extern "C" void kernel_launch(void* const* d_in, const int* in_sizes, int n_in,
                              void* d_out, int out_size, void* d_ws, size_t ws_size,
                              hipStream_t stream) {
    const int* labels = (const int*)d_in[0];
    const float* emb = (const float*)d_in[1];
    float* out = (float*)d_out;

    char* ws = (char*)d_ws;
    u16* ebf = (u16*)ws;                                     // 4 MB
    float* sq = (float*)(ws + (size_t)NS * DD * 2);          // 32 KB
    u32* mxk = (u32*)(ws + (size_t)NS * DD * 2 + NS * 4);
    u32* mnk = mxk + NS;

    prep_kernel<<<NS * DD / 4 / 256, 256, 0, stream>>>(emb, ebf, sq, mxk, mnk, out);
    tile_kernel<<<2080, 256, 0, stream>>>(ebf, labels, mxk, mnk);
    finalize_kernel<<<NS / 256, 256, 0, stream>>>(mxk, mnk, sq, out);
}